// Round 5
// baseline (162.041 us; speedup 1.0000x reference)
//
#include <hip/hip_runtime.h>
#include <hip/hip_bf16.h>

typedef __attribute__((ext_vector_type(8))) short bf16x8;
typedef __attribute__((ext_vector_type(4))) float f32x4;
typedef __attribute__((ext_vector_type(4))) unsigned int u32x4;
typedef unsigned short u16;
typedef unsigned int u32;

static constexpr int KDIM  = 784;   // 28*28
static constexpr int KP    = 800;   // K padded (weff zero-pads k>=784)
static constexpr int NDIM  = 300;
static constexpr int NP    = 320;
static constexpr int DDIM  = 10;
static constexpr int BM    = 96;    // rows per block
static constexpr int BK    = 32;
static constexpr int NSTEP = 25;
static constexpr int BUFU  = NP * BK;  // 10240 u16 = 20KB per B buffer
static constexpr int H1STR = 328;
static constexpr int NTHR  = 640;   // 10 waves: 2m x 5n
static constexpr int NROW  = 65536;

__device__ __forceinline__ u16 f2bf(float f) {
  unsigned u = __builtin_bit_cast(unsigned, f);
  u += 0x7fffu + ((u >> 16) & 1u);   // RNE
  return (u16)(u >> 16);
}
__device__ __forceinline__ u32 pk2(float a, float b) {
  u32 r;
  asm("v_cvt_pk_bf16_f32 %0, %1, %2" : "=v"(r) : "v"(a), "v"(b));
  return r;
}
__device__ __forceinline__ void gll16(const void* g, void* l) {
  __builtin_amdgcn_global_load_lds(
      (const __attribute__((address_space(1))) void*)g,
      (__attribute__((address_space(3))) void*)l, 16, 0, 0);
}

// ---- Kernel A: fold conv into first linear layer; weff_t[n][k] bf16, zero-padded ----
__global__ void build_weff(const float* __restrict__ cw,
                           const float* __restrict__ w1,
                           u16* __restrict__ weff) {
  int idx = blockIdx.x * 256 + threadIdx.x;
  if (idx >= NP * KP) return;
  int n = idx / KP;
  int k = idx - n * KP;
  float acc = 0.f;
  if (n < NDIM && k < KDIM) {
    int r = k / 28, c = k - (k / 28) * 28;
    #pragma unroll
    for (int dr = 0; dr < 3; ++dr) {
      int orr = r - dr;
      if ((unsigned)orr < 26u) {
        #pragma unroll
        for (int dc = 0; dc < 3; ++dc) {
          int oc = c - dc;
          if ((unsigned)oc < 26u)
            acc += cw[dr * 3 + dc] * w1[(orr * 26 + oc) * NDIM + n];
        }
      }
    }
  }
  weff[n * KP + k] = f2bf(acc);
}

// ---- Kernel B: out = relu(x @ Weff + b1) @ w2 + b2 ----
// 640 thr (10 waves, 2m x 5n). A: global->reg, 1 step ahead (L1-shared).
// B: global_load_lds, 3 LDS buffers, staged 2 steps ahead, counted vmcnt +
// raw s_barrier (loads stay in flight across barriers; never drain in-loop).
__global__ void __launch_bounds__(NTHR, 3)
fused_mlp(const float* __restrict__ x, const float* __restrict__ b1,
          const float* __restrict__ w2, const float* __restrict__ b2,
          const u16* __restrict__ weff, float* __restrict__ out) {
  // buffers: 3 x 10240 u16 (60KB). epilogue overlay: H1[96][328] + W2T[16][328] = 73472B
  __shared__ __align__(16) u16 lds[36736];

  const int tid  = threadIdx.x;
  const int wv   = tid >> 6;
  const int lane = tid & 63;
  const int l16  = lane & 15;
  const int lhi  = lane >> 4;     // 0..3
  const int wm   = wv / 5;        // 0..1 -> rows wm*48
  const int wn   = wv % 5;        // 0..4 -> cols wn*64
  const int bm   = blockIdx.x * BM;

  // B staging: flat chunk ids tid and tid+640 over 1280 chunks (q=k-oct, r=n)
  const int f1 = tid + NTHR;
  const int q0 = tid / NP, r0 = tid - q0 * NP;
  const int q1 = f1 / NP,  r1 = f1 - q1 * NP;

  // A row pointers (clamped for the partial last block)
  const float* xrow[3];
  #pragma unroll
  for (int mi = 0; mi < 3; ++mi) {
    int row = bm + wm * 48 + mi * 16 + l16;
    if (row > NROW - 1) row = NROW - 1;
    xrow[mi] = x + (size_t)row * KDIM;
  }

  f32x4 acc[3][4];
  #pragma unroll
  for (int mi = 0; mi < 3; ++mi)
    #pragma unroll
    for (int ni = 0; ni < 4; ++ni)
      acc[mi][ni] = (f32x4){0.f, 0.f, 0.f, 0.f};

  f32x4 aA[6], aB[6];

  auto loadA = [&](f32x4 (&dst)[6], int t) {
    int kk = t * BK + lhi * 8;
    if (kk >= KDIM) kk = 0;          // tail lanes: A garbage x B zero-pad = 0
    #pragma unroll
    for (int mi = 0; mi < 3; ++mi) {
      dst[2 * mi]     = *reinterpret_cast<const f32x4*>(xrow[mi] + kk);
      dst[2 * mi + 1] = *reinterpret_cast<const f32x4*>(xrow[mi] + kk + 4);
    }
  };
  auto stageB = [&](u16* buf, int t) {
    int k0 = (t < NSTEP) ? t * BK : 0;   // dummy stage keeps vmcnt counting uniform
    gll16(weff + (size_t)r0 * KP + k0 + q0 * 8, (char*)buf + tid * 16);
    gll16(weff + (size_t)r1 * KP + k0 + q1 * 8, (char*)buf + (NTHR + tid) * 16);
  };
  auto compute = [&](const f32x4 (&aCur)[6], const u16* bR) {
    bf16x8 bfr[4];
    #pragma unroll
    for (int ni = 0; ni < 4; ++ni)
      bfr[ni] = *reinterpret_cast<const bf16x8*>(
          bR + (lhi * NP + wn * 64 + ni * 16 + l16) * 8);
    #pragma unroll
    for (int mi = 0; mi < 3; ++mi) {
      u32x4 amu = { pk2(aCur[2*mi][0],   aCur[2*mi][1]),
                    pk2(aCur[2*mi][2],   aCur[2*mi][3]),
                    pk2(aCur[2*mi+1][0], aCur[2*mi+1][1]),
                    pk2(aCur[2*mi+1][2], aCur[2*mi+1][3]) };
      bf16x8 am = __builtin_bit_cast(bf16x8, amu);
      #pragma unroll
      for (int ni = 0; ni < 4; ++ni)
        acc[mi][ni] = __builtin_amdgcn_mfma_f32_16x16x32_bf16(am, bfr[ni], acc[mi][ni], 0, 0, 0);
    }
  };

  u16 *b0 = lds, *bu1 = lds + BUFU, *bu2 = lds + 2 * BUFU;

  // prologue: A(0)->regs; B(0)->b0, B(1)->b1 in flight
  loadA(aA, 0);
  stageB(b0, 0);
  stageB(bu1, 1);
  asm volatile("s_waitcnt vmcnt(2)" ::: "memory");   // B(0) landed; B(1) in flight
  __builtin_amdgcn_s_barrier();
  __builtin_amdgcn_sched_barrier(0);

  u16 *bR = b0, *bN1 = bu1, *bN2 = bu2;
  for (int i = 0; i < 12; ++i) {
    // step t = 2i : consume aA/bR, prefetch A(t+1)->aB, stage B(t+2)->bN2
    loadA(aB, 2 * i + 1);
    stageB(bN2, 2 * i + 2);
    compute(aA, bR);
    asm volatile("s_waitcnt vmcnt(8)" ::: "memory"); // drain B(t+1); keep A(t+1)+B(t+2)
    __builtin_amdgcn_s_barrier();
    __builtin_amdgcn_sched_barrier(0);
    { u16* t_ = bR; bR = bN1; bN1 = bN2; bN2 = t_; }
    // step t = 2i+1
    loadA(aA, 2 * i + 2);
    stageB(bN2, 2 * i + 3);                           // i==11 -> dummy (t+2==25)
    compute(aB, bR);
    asm volatile("s_waitcnt vmcnt(8)" ::: "memory");
    __builtin_amdgcn_s_barrier();
    __builtin_amdgcn_sched_barrier(0);
    { u16* t_ = bR; bR = bN1; bN1 = bN2; bN2 = t_; }
  }
  compute(aA, bR);   // t = 24
  __syncthreads();   // full drain before LDS overlay

  // ---- epilogue: h1 = relu(acc + b1); out = h1 @ w2 + b2 ----
  u16* H1  = lds;                  // [96][328]
  u16* W2T = lds + 96 * H1STR;     // [16][328]

  for (int i = tid; i < 16 * NP; i += NTHR) {
    int d = i / NP, n = i - (i / NP) * NP;
    float v = (d < DDIM && n < NDIM) ? w2[n * DDIM + d] : 0.f;
    W2T[d * H1STR + n] = f2bf(v);
  }
  float biasv[4];
  #pragma unroll
  for (int ni = 0; ni < 4; ++ni) {
    int col = wn * 64 + ni * 16 + l16;
    biasv[ni] = (col < NDIM) ? b1[col] : 0.f;
  }
  #pragma unroll
  for (int mi = 0; mi < 3; ++mi) {
    #pragma unroll
    for (int ni = 0; ni < 4; ++ni) {
      int col = wn * 64 + ni * 16 + l16;
      int rb  = wm * 48 + mi * 16 + lhi * 4;
      #pragma unroll
      for (int r = 0; r < 4; ++r) {
        float h = acc[mi][ni][r] + biasv[ni];
        H1[(rb + r) * H1STR + col] = f2bf(fmaxf(h, 0.f));
      }
    }
  }
  __syncthreads();

  if (wv < 6) {                    // 6 waves cover 96 rows
    f32x4 a2c = (f32x4){0.f, 0.f, 0.f, 0.f};
    #pragma unroll
    for (int ks = 0; ks < NP / 32; ++ks) {
      bf16x8 a2 = *reinterpret_cast<const bf16x8*>(H1 + (wv * 16 + l16) * H1STR + ks * 32 + lhi * 8);
      bf16x8 bw = *reinterpret_cast<const bf16x8*>(W2T + l16 * H1STR + ks * 32 + lhi * 8);
      a2c = __builtin_amdgcn_mfma_f32_16x16x32_bf16(a2, bw, a2c, 0, 0, 0);
    }
    if (l16 < DDIM) {
      float bb = b2[l16];
      #pragma unroll
      for (int r = 0; r < 4; ++r) {
        int row = bm + wv * 16 + lhi * 4 + r;
        if (row < NROW) out[(size_t)row * DDIM + l16] = a2c[r] + bb;
      }
    }
  }
}

extern "C" void kernel_launch(void* const* d_in, const int* in_sizes, int n_in,
                              void* d_out, int out_size, void* d_ws, size_t ws_size,
                              hipStream_t stream) {
  const float* x  = (const float*)d_in[0];
  const float* cw = (const float*)d_in[1];
  const float* w1 = (const float*)d_in[2];
  const float* b1 = (const float*)d_in[3];
  const float* w2 = (const float*)d_in[4];
  const float* b2 = (const float*)d_in[5];
  float* out = (float*)d_out;
  u16* weff = (u16*)d_ws;   // 320*800*2 = 512000 bytes

  hipLaunchKernelGGL(build_weff, dim3((NP * KP + 255) / 256), dim3(256), 0, stream,
                     cw, w1, weff);
  hipLaunchKernelGGL(fused_mlp, dim3((NROW + BM - 1) / BM), dim3(NTHR), 0, stream,
                     x, b1, w2, b2, weff, out);
}

// Round 6
// 134.695 us; speedup vs baseline: 1.2030x; 1.2030x over previous
//
#include <hip/hip_runtime.h>
#include <hip/hip_bf16.h>

typedef __attribute__((ext_vector_type(8))) short bf16x8;
typedef __attribute__((ext_vector_type(4))) float f32x4;
typedef unsigned short u16;
typedef unsigned int u32;

static constexpr int KDIM  = 784;   // 28*28
static constexpr int KP    = 800;   // K padded (weff zero-pads k>=784)
static constexpr int NDIM  = 300;
static constexpr int NP    = 320;
static constexpr int DDIM  = 10;
static constexpr int BM    = 64;    // rows per block (16 per wave)
static constexpr int BK    = 32;
static constexpr int NSTEP = 25;
static constexpr int BUFU  = NP * BK;   // 10240 u16 = 20KB per B buffer
static constexpr int H1STR = 328;
static constexpr int NROW  = 65536;

__device__ __forceinline__ u16 f2bf(float f) {
  unsigned u = __builtin_bit_cast(unsigned, f);
  u += 0x7fffu + ((u >> 16) & 1u);   // RNE
  return (u16)(u >> 16);
}
__device__ __forceinline__ u32 pk2(float a, float b) {
  u32 r;
  asm("v_cvt_pk_bf16_f32 %0, %1, %2" : "=v"(r) : "v"(a), "v"(b));
  return r;
}
__device__ __forceinline__ void gll16(const void* g, void* l) {
  __builtin_amdgcn_global_load_lds(
      (const __attribute__((address_space(1))) void*)g,
      (__attribute__((address_space(3))) void*)l, 16, 0, 0);
}

// ---- Kernel A: fold conv into first linear layer; weff_t[n][k] bf16, zero-padded ----
__global__ void build_weff(const float* __restrict__ cw,
                           const float* __restrict__ w1,
                           u16* __restrict__ weff) {
  int idx = blockIdx.x * 256 + threadIdx.x;
  if (idx >= NP * KP) return;
  int n = idx / KP;
  int k = idx - n * KP;
  float acc = 0.f;
  if (n < NDIM && k < KDIM) {
    int r = k / 28, c = k - (k / 28) * 28;
    #pragma unroll
    for (int dr = 0; dr < 3; ++dr) {
      int orr = r - dr;
      if ((unsigned)orr < 26u) {
        #pragma unroll
        for (int dc = 0; dc < 3; ++dc) {
          int oc = c - dc;
          if ((unsigned)oc < 26u)
            acc += cw[dr * 3 + dc] * w1[(orr * 26 + oc) * NDIM + n];
        }
      }
    }
  }
  weff[n * KP + k] = f2bf(acc);
}

// ---- Kernel B: out = relu(x @ Weff + b1) @ w2 + b2 ----
// 256 thr / 4 waves. Each wave owns 16 rows x full N=320.
// ALL of A (16 rows x 800) lives in registers as bf16 (loaded once, prologue).
// K-loop: only B staged (L2-resident weff) via global_load_lds dbuf,
// one __syncthreads per step. Epilogue barrier-free (per-wave H1 rows).
__global__ void __launch_bounds__(256, 2)
fused_mlp(const float* __restrict__ x, const float* __restrict__ b1,
          const float* __restrict__ w2, const float* __restrict__ b2,
          const u16* __restrict__ weff, float* __restrict__ out) {
  // LDS: B dbuf 2x20480B at [0,40960); W2T[16][328] at [41984,52480).
  // Epilogue H1[64][328] overlays [0,41984).
  __shared__ __align__(16) u16 lds[26240];   // 52480 B
  u16* W2T = lds + 20992;                     // u16 offset 41984/2

  const int tid  = threadIdx.x;
  const int wv   = tid >> 6;
  const int lane = tid & 63;
  const int l16  = lane & 15;
  const int lhi  = lane >> 4;     // 0..3
  const int bm   = blockIdx.x * BM;

  // B staging chunk ids: 1280 chunks of 16B, 5 per thread (uniform)
  int cQ[5], cN[5];
  #pragma unroll
  for (int i = 0; i < 5; ++i) {
    int c = tid + i * 256;
    int q = c / NP;
    cQ[i] = q;
    cN[i] = c - q * NP;
  }

  // --- stage B(0) first so L2 fetch overlaps the A-register load burst ---
  auto stageB = [&](u16* buf, int t) {
    int k0 = t * BK;
    #pragma unroll
    for (int i = 0; i < 5; ++i)
      gll16(weff + (size_t)cN[i] * KP + k0 + cQ[i] * 8,
            (char*)buf + (tid + i * 256) * 16);
  };
  stageB(lds, 0);

  // --- W2T build (prologue; region disjoint from B buffers) ---
  for (int i = tid; i < 16 * NP; i += 256) {
    int d = i / NP, n = i - (i / NP) * NP;
    float v = (d < DDIM && n < NDIM) ? w2[n * DDIM + d] : 0.f;
    W2T[d * H1STR + n] = f2bf(v);
  }

  // --- A: 16 rows x 800 per wave -> 25 bf16x8 per lane (100 VGPRs) ---
  const float* xr = x + (size_t)(bm + wv * 16 + l16) * KDIM;
  bf16x8 aAll[25];
  #pragma unroll
  for (int t = 0; t < NSTEP; ++t) {
    int kk = t * BK + lhi * 8;
    if (kk + 8 > KDIM) kk = 0;     // t=24, lhi>=2: garbage x B-zero-pad = 0
    f32x4 v0 = *reinterpret_cast<const f32x4*>(xr + kk);
    f32x4 v1 = *reinterpret_cast<const f32x4*>(xr + kk + 4);
    u32 p0 = pk2(v0[0], v0[1]), p1 = pk2(v0[2], v0[3]);
    u32 p2 = pk2(v1[0], v1[1]), p3 = pk2(v1[2], v1[3]);
    aAll[t] = __builtin_bit_cast(bf16x8,
        (__attribute__((ext_vector_type(4))) u32){p0, p1, p2, p3});
  }

  f32x4 acc[20];
  #pragma unroll
  for (int ni = 0; ni < 20; ++ni)
    acc[ni] = (f32x4){0.f, 0.f, 0.f, 0.f};

  __syncthreads();    // B(0) staged (gll drained by syncthreads' vmcnt(0))

  // --- K-loop: 25 steps, 1 barrier/step, B dbuf ---
  #pragma unroll
  for (int t = 0; t < NSTEP; ++t) {
    const u16* buf = lds + (t & 1) * BUFU;
    if (t + 1 < NSTEP)
      stageB(lds + ((t + 1) & 1) * BUFU, t + 1);   // async into other buffer
    const int fbase = lhi * NP * 8;                 // chunk-major: (lhi*320+n)*8 u16
    #pragma unroll
    for (int ni = 0; ni < 20; ++ni) {
      bf16x8 bf = *reinterpret_cast<const bf16x8*>(
          buf + fbase + (ni * 16 + l16) * 8);
      acc[ni] = __builtin_amdgcn_mfma_f32_16x16x32_bf16(aAll[t], bf, acc[ni], 0, 0, 0);
    }
    __syncthreads();   // drains stage(t+1) gll + guards buffer reuse
  }

  // --- epilogue (barrier-free): h1 rows are wave-private ---
  u16* H1 = lds;     // [64][328] overlays B buffers (all waves past final barrier)
  #pragma unroll
  for (int ni = 0; ni < 20; ++ni) {
    int col = ni * 16 + l16;
    float bias = (col < NDIM) ? b1[col] : 0.f;
    int rbase = wv * 16 + lhi * 4;
    #pragma unroll
    for (int r = 0; r < 4; ++r) {
      float h = acc[ni][r] + bias;
      H1[(rbase + r) * H1STR + col] = f2bf(fmaxf(h, 0.f));
    }
  }
  // wave reads only its own 16 rows (lgkmcnt ordering within wave suffices)
  f32x4 a2c = (f32x4){0.f, 0.f, 0.f, 0.f};
  #pragma unroll
  for (int ks = 0; ks < NP / 32; ++ks) {
    bf16x8 a2 = *reinterpret_cast<const bf16x8*>(
        H1 + (wv * 16 + l16) * H1STR + ks * 32 + lhi * 8);
    bf16x8 bw = *reinterpret_cast<const bf16x8*>(
        W2T + l16 * H1STR + ks * 32 + lhi * 8);
    a2c = __builtin_amdgcn_mfma_f32_16x16x32_bf16(a2, bw, a2c, 0, 0, 0);
  }
  if (l16 < DDIM) {
    float bb = b2[l16];
    #pragma unroll
    for (int r = 0; r < 4; ++r) {
      int row = bm + wv * 16 + lhi * 4 + r;
      out[(size_t)row * DDIM + l16] = a2c[r] + bb;
    }
  }
}

extern "C" void kernel_launch(void* const* d_in, const int* in_sizes, int n_in,
                              void* d_out, int out_size, void* d_ws, size_t ws_size,
                              hipStream_t stream) {
  const float* x  = (const float*)d_in[0];
  const float* cw = (const float*)d_in[1];
  const float* w1 = (const float*)d_in[2];
  const float* b1 = (const float*)d_in[3];
  const float* w2 = (const float*)d_in[4];
  const float* b2 = (const float*)d_in[5];
  float* out = (float*)d_out;
  u16* weff = (u16*)d_ws;   // 320*800*2 = 512000 bytes

  hipLaunchKernelGGL(build_weff, dim3((NP * KP + 255) / 256), dim3(256), 0, stream,
                     cw, w1, weff);
  hipLaunchKernelGGL(fused_mlp, dim3(NROW / BM), dim3(256), 0, stream,
                     x, b1, w2, b2, weff, out);
}

// Round 7
// 118.080 us; speedup vs baseline: 1.3723x; 1.1407x over previous
//
#include <hip/hip_runtime.h>
#include <hip/hip_bf16.h>

typedef __attribute__((ext_vector_type(8))) short bf16x8;
typedef __attribute__((ext_vector_type(4))) float f32x4;
typedef __attribute__((ext_vector_type(4))) unsigned int u32x4;
typedef unsigned short u16;
typedef unsigned int u32;

static constexpr int KDIM  = 784;   // 28*28
static constexpr int KP    = 800;   // K padded (weff zero-pads k>=784)
static constexpr int NDIM  = 300;
static constexpr int NP    = 320;
static constexpr int DDIM  = 10;
static constexpr int BM    = 64;    // rows per block
static constexpr int BK    = 32;
static constexpr int NSTEP = 25;
static constexpr int H1STR = 328;
static constexpr int NROW  = 65536;

__device__ __forceinline__ u16 f2bf(float f) {
  unsigned u = __builtin_bit_cast(unsigned, f);
  u += 0x7fffu + ((u >> 16) & 1u);   // RNE
  return (u16)(u >> 16);
}
__device__ __forceinline__ u32 pk2(float a, float b) {
  u32 r;
  asm("v_cvt_pk_bf16_f32 %0, %1, %2" : "=v"(r) : "v"(a), "v"(b));
  return r;
}

// ---- Kernel A: fold conv into first linear layer; weff_t[n][k] bf16, zero-padded ----
__global__ void build_weff(const float* __restrict__ cw,
                           const float* __restrict__ w1,
                           u16* __restrict__ weff) {
  int idx = blockIdx.x * 256 + threadIdx.x;
  if (idx >= NP * KP) return;
  int n = idx / KP;
  int k = idx - n * KP;
  float acc = 0.f;
  if (n < NDIM && k < KDIM) {
    int r = k / 28, c = k - (k / 28) * 28;
    #pragma unroll
    for (int dr = 0; dr < 3; ++dr) {
      int orr = r - dr;
      if ((unsigned)orr < 26u) {
        #pragma unroll
        for (int dc = 0; dc < 3; ++dc) {
          int oc = c - dc;
          if ((unsigned)oc < 26u)
            acc += cw[dr * 3 + dc] * w1[(orr * 26 + oc) * NDIM + n];
        }
      }
    }
  }
  weff[n * KP + k] = f2bf(acc);
}

// ---- Kernel B: out = relu(x @ Weff + b1) @ w2 + b2 ----
// 256 thr / 4 waves. BARRIER-FREE K-loop: no LDS in the main loop.
// Per wave: acc = all 64 rows x its 80-col slice (4x5 16x16x32 frags).
// A frags: global->reg per wave (L1-shared across waves), E/O ping-pong.
// B frags: global->reg per wave (weff L2-resident), E/O ping-pong.
// LDS used only for the tiny second-layer epilogue (1 barrier total).
__global__ void __launch_bounds__(256, 2)
fused_mlp(const float* __restrict__ x, const float* __restrict__ b1,
          const float* __restrict__ w2, const float* __restrict__ b2,
          const u16* __restrict__ weff, float* __restrict__ out) {
  __shared__ __align__(16) u16 lds[26240];   // W2T[16][328] @0 ; H1[64][328] @5248
  u16* W2T = lds;
  u16* H1  = lds + 16 * H1STR;

  const int tid  = threadIdx.x;
  const int wv   = tid >> 6;
  const int lane = tid & 63;
  const int l16  = lane & 15;
  const int lhi  = lane >> 4;     // 0..3
  const int bm   = blockIdx.x * BM;

  // base pointers: A rows (4 mi) and B cols (5 ni)
  const float* xr[4];
  #pragma unroll
  for (int mi = 0; mi < 4; ++mi)
    xr[mi] = x + (size_t)(bm + mi * 16 + l16) * KDIM;
  const u16* wr[5];
  #pragma unroll
  for (int ni = 0; ni < 5; ++ni)
    wr[ni] = weff + (size_t)(wv * 80 + ni * 16 + l16) * KP;

  // prologue LDS work: W2T[d][n] (disjoint from everything; visible after barrier)
  for (int i = tid; i < 16 * NP; i += 256) {
    int d = i / NP, n = i - (i / NP) * NP;
    float v = (d < DDIM && n < NDIM) ? w2[n * DDIM + d] : 0.f;
    W2T[d * H1STR + n] = f2bf(v);
  }
  float biasv[5];
  #pragma unroll
  for (int ni = 0; ni < 5; ++ni) {
    int col = wv * 80 + ni * 16 + l16;
    biasv[ni] = (col < NDIM) ? b1[col] : 0.f;
  }

  f32x4 acc[4][5];
  #pragma unroll
  for (int mi = 0; mi < 4; ++mi)
    #pragma unroll
    for (int ni = 0; ni < 5; ++ni)
      acc[mi][ni] = (f32x4){0.f, 0.f, 0.f, 0.f};

  f32x4  aE[8], aO[8];
  bf16x8 bE[5], bO[5];

  auto issueA = [&](f32x4 (&a)[8], int t) {
    int kk = t * BK + lhi * 8;
    if (kk + 8 > KDIM) kk = 0;     // t=24, lhi>=2: garbage x B-zero-pad = 0
    #pragma unroll
    for (int mi = 0; mi < 4; ++mi) {
      a[2 * mi]     = *reinterpret_cast<const f32x4*>(xr[mi] + kk);
      a[2 * mi + 1] = *reinterpret_cast<const f32x4*>(xr[mi] + kk + 4);
    }
  };
  auto issueB = [&](bf16x8 (&b)[5], int t) {
    #pragma unroll
    for (int ni = 0; ni < 5; ++ni)
      b[ni] = *reinterpret_cast<const bf16x8*>(wr[ni] + t * BK + lhi * 8);
  };
  auto consume = [&](const f32x4 (&a)[8], const bf16x8 (&b)[5]) {
    #pragma unroll
    for (int mi = 0; mi < 4; ++mi) {
      u32x4 amu = { pk2(a[2*mi][0],   a[2*mi][1]),
                    pk2(a[2*mi][2],   a[2*mi][3]),
                    pk2(a[2*mi+1][0], a[2*mi+1][1]),
                    pk2(a[2*mi+1][2], a[2*mi+1][3]) };
      bf16x8 am = __builtin_bit_cast(bf16x8, amu);
      #pragma unroll
      for (int ni = 0; ni < 5; ++ni)
        acc[mi][ni] = __builtin_amdgcn_mfma_f32_16x16x32_bf16(am, b[ni], acc[mi][ni], 0, 0, 0);
    }
  };

  // ---- barrier-free software-pipelined K-loop (25 steps) ----
  issueA(aE, 0);
  issueB(bE, 0);
  for (int i = 0; i < 12; ++i) {
    issueA(aO, 2 * i + 1);
    issueB(bO, 2 * i + 1);
    consume(aE, bE);               // waits only on E-loads (O in flight)
    issueA(aE, 2 * i + 2);
    issueB(bE, 2 * i + 2);
    consume(aO, bO);
  }
  consume(aE, bE);                 // t = 24

  // ---- epilogue: h1 = relu(acc + b1) -> H1; out = h1 @ w2 + b2 ----
  #pragma unroll
  for (int mi = 0; mi < 4; ++mi) {
    #pragma unroll
    for (int ni = 0; ni < 5; ++ni) {
      int col = wv * 80 + ni * 16 + l16;
      int rb  = mi * 16 + lhi * 4;
      #pragma unroll
      for (int r = 0; r < 4; ++r) {
        float h = acc[mi][ni][r] + biasv[ni];
        H1[(rb + r) * H1STR + col] = f2bf(fmaxf(h, 0.f));
      }
    }
  }
  __syncthreads();   // the ONLY barrier: H1 + W2T visible to all waves

  f32x4 a2c = (f32x4){0.f, 0.f, 0.f, 0.f};
  #pragma unroll
  for (int ks = 0; ks < NP / 32; ++ks) {
    bf16x8 a2 = *reinterpret_cast<const bf16x8*>(
        H1 + (wv * 16 + l16) * H1STR + ks * 32 + lhi * 8);
    bf16x8 bw = *reinterpret_cast<const bf16x8*>(
        W2T + l16 * H1STR + ks * 32 + lhi * 8);
    a2c = __builtin_amdgcn_mfma_f32_16x16x32_bf16(a2, bw, a2c, 0, 0, 0);
  }
  if (l16 < DDIM) {
    float bb = b2[l16];
    #pragma unroll
    for (int r = 0; r < 4; ++r) {
      int row = bm + wv * 16 + lhi * 4 + r;
      out[(size_t)row * DDIM + l16] = a2c[r] + bb;
    }
  }
}

extern "C" void kernel_launch(void* const* d_in, const int* in_sizes, int n_in,
                              void* d_out, int out_size, void* d_ws, size_t ws_size,
                              hipStream_t stream) {
  const float* x  = (const float*)d_in[0];
  const float* cw = (const float*)d_in[1];
  const float* w1 = (const float*)d_in[2];
  const float* b1 = (const float*)d_in[3];
  const float* w2 = (const float*)d_in[4];
  const float* b2 = (const float*)d_in[5];
  float* out = (float*)d_out;
  u16* weff = (u16*)d_ws;   // 320*800*2 = 512000 bytes

  hipLaunchKernelGGL(build_weff, dim3((NP * KP + 255) / 256), dim3(256), 0, stream,
                     cw, w1, weff);
  hipLaunchKernelGGL(fused_mlp, dim3(NROW / BM), dim3(256), 0, stream,
                     x, b1, w2, b2, weff, out);
}

// Round 8
// 78.360 us; speedup vs baseline: 2.0679x; 1.5069x over previous
//
#include <hip/hip_runtime.h>
#include <hip/hip_bf16.h>

typedef __attribute__((ext_vector_type(8))) short bf16x8;
typedef __attribute__((ext_vector_type(4))) float f32x4;
typedef __attribute__((ext_vector_type(4))) unsigned int u32x4;
typedef unsigned short u16;
typedef unsigned int u32;

static constexpr int KDIM  = 784;   // 28*28
static constexpr int KP    = 800;   // K padded (weff zero-pads k>=784 and n>=300)
static constexpr int NDIM  = 300;
static constexpr int NP    = 320;
static constexpr int DDIM  = 10;
static constexpr int BM    = 64;
static constexpr int BK    = 32;
static constexpr int NSTEP = 25;
static constexpr int H1STR = 328;
static constexpr int NROW  = 65536;
// LDS bytes: A fp32 3 x 8192 @ 0; B bf16 2 x 20480 @ 24576. Total 65536.
static constexpr int ABYTES = 8192;
static constexpr int BBYTES = 20480;
static constexpr int BBASE  = 24576;

__device__ __forceinline__ u16 f2bf(float f) {
  unsigned u = __builtin_bit_cast(unsigned, f);
  u += 0x7fffu + ((u >> 16) & 1u);   // RNE
  return (u16)(u >> 16);
}
__device__ __forceinline__ u32 pk2(float a, float b) {
  u32 r;
  asm("v_cvt_pk_bf16_f32 %0, %1, %2" : "=v"(r) : "v"(a), "v"(b));
  return r;
}
__device__ __forceinline__ void gll16(const void* g, void* l) {
  __builtin_amdgcn_global_load_lds(
      (const __attribute__((address_space(1))) void*)g,
      (__attribute__((address_space(3))) void*)l, 16, 0, 0);
}

// ---- Kernel A: fold conv into first linear layer; weff_t[n][k] bf16, zero-padded ----
__global__ void build_weff(const float* __restrict__ cw,
                           const float* __restrict__ w1,
                           u16* __restrict__ weff) {
  int idx = blockIdx.x * 256 + threadIdx.x;
  if (idx >= NP * KP) return;
  int n = idx / KP;
  int k = idx - n * KP;
  float acc = 0.f;
  if (n < NDIM && k < KDIM) {
    int r = k / 28, c = k - (k / 28) * 28;
    #pragma unroll
    for (int dr = 0; dr < 3; ++dr) {
      int orr = r - dr;
      if ((unsigned)orr < 26u) {
        #pragma unroll
        for (int dc = 0; dc < 3; ++dc) {
          int oc = c - dc;
          if ((unsigned)oc < 26u)
            acc += cw[dr * 3 + dc] * w1[(orr * 26 + oc) * NDIM + n];
        }
      }
    }
  }
  weff[n * KP + k] = f2bf(acc);
}

// ---- Kernel B: out = relu(x @ Weff + b1) @ w2 + b2 ----
// 256 thr / 4 waves; wave wv owns 64 rows x cols wv*80..+80 (4x5 16x16x32 frags).
// ALL staging via global_load_lds (nothing for the compiler to sink):
//   A (x, fp32): 3 buffers, staged 2 steps ahead  (HBM/L3 latency budget ~2 steps)
//   B (weff, bf16, L2-resident): 2 buffers, staged 1 step ahead
// Uniform 7 gll/thread/step; pre-barrier s_waitcnt vmcnt(2) keeps A(t+2) in
// flight across the barrier (never a full drain in the loop).
// LDS slot maps XOR-swizzled: global reads stay line-coalesced, LDS frag
// reads spread evenly over all 32 banks.
__global__ void __launch_bounds__(256, 2)
fused_mlp(const float* __restrict__ x, const float* __restrict__ b1,
          const float* __restrict__ w2, const float* __restrict__ b2,
          const u16* __restrict__ weff, float* __restrict__ out) {
  __shared__ __align__(16) u16 lds[32768];   // 65536 B -> 2 blocks/CU

  const int tid  = threadIdx.x;
  const int wv   = tid >> 6;
  const int lane = tid & 63;
  const int l16  = lane & 15;
  const int lhi  = lane >> 4;     // 0..3
  const int bm   = blockIdx.x * BM;
  const int wvn  = wv * 80;

  // --- A staging ids (2 chunks/thread): slot s = tid + it*256 in [0,512)
  //     row rA = s>>3, lds-chunk c = s&7, global chunk qg = c ^ (rA&7)
  int aRow[2], aQg[2];
  #pragma unroll
  for (int it = 0; it < 2; ++it) {
    int s = tid + it * 256;
    aRow[it] = s >> 3;
    aQg[it]  = (s & 7) ^ (aRow[it] & 7);
  }
  // --- B staging ids (5 chunks/thread): slot s = tid + i*256 in [0,1280)
  //     row rB = s>>2, lds-chunk c = s&3, global chunk qg = c ^ (rB&3)
  int bRow[5], bQg[5];
  #pragma unroll
  for (int i = 0; i < 5; ++i) {
    int s = tid + i * 256;
    bRow[i] = s >> 2;
    bQg[i]  = (s & 3) ^ (bRow[i] & 3);
  }

  auto stageA = [&](int bufi, int t) {
    char* base = (char*)lds + bufi * ABYTES;
    int k0 = (t < NSTEP) ? t * BK : 0;
    #pragma unroll
    for (int it = 0; it < 2; ++it) {
      int kof = k0 + aQg[it] * 4;
      if (kof >= KDIM) kof = aQg[it] * 4;   // t=24 pad chunks: safe finite garbage
      gll16(x + (size_t)(bm + aRow[it]) * KDIM + kof,
            base + (tid + it * 256) * 16);
    }
  };
  auto stageB = [&](int bufi, int t) {
    char* base = (char*)lds + BBASE + bufi * BBYTES;
    int k0 = (t < NSTEP) ? t * BK : 0;
    #pragma unroll
    for (int i = 0; i < 5; ++i)
      gll16(weff + (size_t)bRow[i] * KP + k0 + bQg[i] * 8,
            base + (tid + i * 256) * 16);
  };

  f32x4 acc[4][5];
  #pragma unroll
  for (int mi = 0; mi < 4; ++mi)
    #pragma unroll
    for (int ni = 0; ni < 5; ++ni)
      acc[mi][ni] = (f32x4){0.f, 0.f, 0.f, 0.f};

  auto compute = [&](int abufi, int bbufi) {
    const f32x4* Af = (const f32x4*)((char*)lds + abufi * ABYTES);
    const u16*   Bb = (const u16*)((char*)lds + BBASE + bbufi * BBYTES);
    bf16x8 bfr[5];
    #pragma unroll
    for (int ni = 0; ni < 5; ++ni) {
      int n = wvn + ni * 16 + l16;
      int slot = n * 4 + (lhi ^ (n & 3));
      bfr[ni] = *reinterpret_cast<const bf16x8*>(Bb + slot * 8);
    }
    #pragma unroll
    for (int mi = 0; mi < 4; ++mi) {
      int R = mi * 16 + l16;
      f32x4 a0 = Af[R * 8 + ((2 * lhi)     ^ (R & 7))];
      f32x4 a1 = Af[R * 8 + ((2 * lhi + 1) ^ (R & 7))];
      u32x4 amu = { pk2(a0[0], a0[1]), pk2(a0[2], a0[3]),
                    pk2(a1[0], a1[1]), pk2(a1[2], a1[3]) };
      bf16x8 am = __builtin_bit_cast(bf16x8, amu);
      #pragma unroll
      for (int ni = 0; ni < 5; ++ni)
        acc[mi][ni] = __builtin_amdgcn_mfma_f32_16x16x32_bf16(am, bfr[ni], acc[mi][ni], 0, 0, 0);
    }
  };

  // ---- prologue: A(0)->a0, B(0)->b0, A(1)->a1; keep A(1) in flight ----
  stageA(0, 0);
  stageB(0, 0);
  stageA(1, 1);
  asm volatile("s_waitcnt vmcnt(2)" ::: "memory");   // drain A(0),B(0); keep A(1)
  __builtin_amdgcn_s_barrier();
  __builtin_amdgcn_sched_barrier(0);

  // ---- main loop: 25 uniform steps, counted vmcnt, one barrier/step ----
  for (int t = 0; t < NSTEP; ++t) {
    stageB((t + 1) & 1, t + 1);        // 5 gll (dummy at t=24)
    stageA((t + 2) % 3, t + 2);        // 2 gll (dummy at t>=23)
    __builtin_amdgcn_sched_barrier(0);
    compute(t % 3, t & 1);
    __builtin_amdgcn_sched_barrier(0);
    asm volatile("s_waitcnt vmcnt(2)" ::: "memory");  // drain A(t+1),B(t+1); keep A(t+2)
    __builtin_amdgcn_s_barrier();
    __builtin_amdgcn_sched_barrier(0);
  }
  __syncthreads();    // full drain (incl. dummies) before LDS overlay

  // ---- epilogue: h1 = relu(acc + b1) -> H1; out = h1 @ w2 + b2 ----
  u16* H1  = lds;                  // [64][328] = 41984 B
  u16* W2T = lds + 64 * H1STR;     // [16][328] = 10496 B (ends 52480 <= 65536)

  for (int i = tid; i < 16 * NP; i += 256) {
    int d = i / NP, n = i - (i / NP) * NP;
    float v = (d < DDIM && n < NDIM) ? w2[n * DDIM + d] : 0.f;
    W2T[d * H1STR + n] = f2bf(v);
  }
  #pragma unroll
  for (int ni = 0; ni < 5; ++ni) {
    int col = wvn + ni * 16 + l16;
    float bias = (col < NDIM) ? b1[col] : 0.f;
    #pragma unroll
    for (int mi = 0; mi < 4; ++mi) {
      int rb = mi * 16 + lhi * 4;
      #pragma unroll
      for (int r = 0; r < 4; ++r) {
        float h = acc[mi][ni][r] + bias;
        H1[(rb + r) * H1STR + col] = f2bf(fmaxf(h, 0.f));
      }
    }
  }
  __syncthreads();

  f32x4 a2c = (f32x4){0.f, 0.f, 0.f, 0.f};
  #pragma unroll
  for (int ks = 0; ks < NP / 32; ++ks) {
    bf16x8 a2 = *reinterpret_cast<const bf16x8*>(
        H1 + (wv * 16 + l16) * H1STR + ks * 32 + lhi * 8);
    bf16x8 bw = *reinterpret_cast<const bf16x8*>(
        W2T + l16 * H1STR + ks * 32 + lhi * 8);
    a2c = __builtin_amdgcn_mfma_f32_16x16x32_bf16(a2, bw, a2c, 0, 0, 0);
  }
  if (l16 < DDIM) {
    float bb = b2[l16];
    #pragma unroll
    for (int r = 0; r < 4; ++r) {
      int row = bm + wv * 16 + lhi * 4 + r;
      out[(size_t)row * DDIM + l16] = a2c[r] + bb;
    }
  }
}

extern "C" void kernel_launch(void* const* d_in, const int* in_sizes, int n_in,
                              void* d_out, int out_size, void* d_ws, size_t ws_size,
                              hipStream_t stream) {
  const float* x  = (const float*)d_in[0];
  const float* cw = (const float*)d_in[1];
  const float* w1 = (const float*)d_in[2];
  const float* b1 = (const float*)d_in[3];
  const float* w2 = (const float*)d_in[4];
  const float* b2 = (const float*)d_in[5];
  float* out = (float*)d_out;
  u16* weff = (u16*)d_ws;   // 320*800*2 = 512000 bytes

  hipLaunchKernelGGL(build_weff, dim3((NP * KP + 255) / 256), dim3(256), 0, stream,
                     cw, w1, weff);
  hipLaunchKernelGGL(fused_mlp, dim3(NROW / BM), dim3(256), 0, stream,
                     x, b1, w2, b2, weff, out);
}

// Round 9
// 61.697 us; speedup vs baseline: 2.6264x; 1.2701x over previous
//
#include <hip/hip_runtime.h>
#include <hip/hip_bf16.h>

typedef __attribute__((ext_vector_type(8))) short bf16x8;
typedef __attribute__((ext_vector_type(4))) float f32x4;
typedef __attribute__((ext_vector_type(4))) unsigned int u32x4;
typedef unsigned short u16;
typedef unsigned int u32;

static constexpr int KDIM  = 784;   // 28*28
static constexpr int KP    = 800;   // K padded (weff zero-pads k>=784 and n>=300)
static constexpr int NDIM  = 300;
static constexpr int NP    = 320;
static constexpr int DDIM  = 10;
static constexpr int BM    = 256;   // rows per block -> grid = 256 = 1 block/CU
static constexpr int BK    = 32;
static constexpr int NSTEP = 25;
static constexpr int H1STR = 328;
static constexpr int NROW  = 65536;
static constexpr int NTHR  = 512;   // 8 waves: 2m x 4n
// LDS bytes: A fp32 3 x 32768 @ 0; B bf16 2 x 20480 @ 98304. Total 139264.
static constexpr int ABYTES = 32768;
static constexpr int BBYTES = 20480;
static constexpr int BBASE  = 98304;

__device__ __forceinline__ u16 f2bf(float f) {
  unsigned u = __builtin_bit_cast(unsigned, f);
  u += 0x7fffu + ((u >> 16) & 1u);   // RNE
  return (u16)(u >> 16);
}
__device__ __forceinline__ u32 pk2(float a, float b) {
  u32 r;
  asm("v_cvt_pk_bf16_f32 %0, %1, %2" : "=v"(r) : "v"(a), "v"(b));
  return r;
}
__device__ __forceinline__ void gll16(const void* g, void* l) {
  __builtin_amdgcn_global_load_lds(
      (const __attribute__((address_space(1))) void*)g,
      (__attribute__((address_space(3))) void*)l, 16, 0, 0);
}

// ---- Kernel A: fold conv into first linear layer; weff_t[n][k] bf16, zero-padded ----
__global__ void build_weff(const float* __restrict__ cw,
                           const float* __restrict__ w1,
                           u16* __restrict__ weff) {
  int idx = blockIdx.x * 256 + threadIdx.x;
  if (idx >= NP * KP) return;
  int n = idx / KP;
  int k = idx - n * KP;
  float acc = 0.f;
  if (n < NDIM && k < KDIM) {
    int r = k / 28, c = k - (k / 28) * 28;
    #pragma unroll
    for (int dr = 0; dr < 3; ++dr) {
      int orr = r - dr;
      if ((unsigned)orr < 26u) {
        #pragma unroll
        for (int dc = 0; dc < 3; ++dc) {
          int oc = c - dc;
          if ((unsigned)oc < 26u)
            acc += cw[dr * 3 + dc] * w1[(orr * 26 + oc) * NDIM + n];
        }
      }
    }
  }
  weff[n * KP + k] = f2bf(acc);
}

// ---- Kernel B: out = relu(x @ Weff + b1) @ w2 + b2 ----
// 512 thr / 8 waves (2m x 4n); per wave 128 rows x 80 cols = 8x5 16x16x32 frags.
// Grid = 256 blocks = exactly 1/CU; weff L2 traffic 128MB total.
// All staging via global_load_lds, uniform 7/thread/step (4 A + 3 B):
//   A (x fp32): 3 buffers, staged 2 steps ahead (~1.5 step-times of latency)
//   B (weff bf16, L2-resident): 2 buffers, 1 step ahead
// Counted s_waitcnt vmcnt(4) before each barrier keeps A(t+2) in flight.
// XOR-swizzled chunk maps: global reads line-coalesced, LDS banks even.
__global__ void __launch_bounds__(NTHR, 2)
fused_mlp(const float* __restrict__ x, const float* __restrict__ b1,
          const float* __restrict__ w2, const float* __restrict__ b2,
          const u16* __restrict__ weff, float* __restrict__ out) {
  __shared__ __align__(16) u16 lds[69632];   // 139264 B -> 1 block/CU

  const int tid  = threadIdx.x;
  const int wv   = tid >> 6;
  const int lane = tid & 63;
  const int l16  = lane & 15;
  const int lhi  = lane >> 4;     // 0..3
  const int wm   = wv >> 2;       // 0..1 -> rows wm*128
  const int wn   = wv & 3;        // 0..3 -> cols wn*80
  const int bm   = blockIdx.x * BM;
  const int wvn  = wn * 80;

  // --- A staging (4 chunks/thread): slot s in [0,2048), row=s>>3, c=s&7,
  //     global chunk qg = c ^ (row&7)  (16B chunks; row = 128B = 8 chunks)
  int aRow[4], aQg[4];
  #pragma unroll
  for (int it = 0; it < 4; ++it) {
    int s = tid + it * NTHR;
    aRow[it] = s >> 3;
    aQg[it]  = (s & 7) ^ (aRow[it] & 7);
  }
  // --- B staging (3 chunks/thread, slots 1024..1279 written twice benignly):
  //     slot s in [0,1280), row=s>>2, c=s&3, qg = c ^ (row&3)
  int bRow[3], bQg[3];
  #pragma unroll
  for (int i = 0; i < 3; ++i) {
    int s = (i < 2) ? (tid + i * NTHR) : (1024 + (tid & 255));
    bRow[i] = s >> 2;
    bQg[i]  = (s & 3) ^ (bRow[i] & 3);
  }

  auto stageA = [&](int bufi, int t) {
    char* base = (char*)lds + bufi * ABYTES;
    int k0 = (t < NSTEP) ? t * BK : 0;
    #pragma unroll
    for (int it = 0; it < 4; ++it) {
      int kof = k0 + aQg[it] * 4;
      if (kof >= KDIM) kof = aQg[it] * 4;   // t=24 pad chunks: finite garbage, B=0
      gll16(x + (size_t)(bm + aRow[it]) * KDIM + kof,
            base + (tid + it * NTHR) * 16);
    }
  };
  auto stageB = [&](int bufi, int t) {
    char* base = (char*)lds + BBASE + bufi * BBYTES;
    int k0 = (t < NSTEP) ? t * BK : 0;
    #pragma unroll
    for (int i = 0; i < 3; ++i) {
      int s = (i < 2) ? (tid + i * NTHR) : (1024 + (tid & 255));
      gll16(weff + (size_t)bRow[i] * KP + k0 + bQg[i] * 8, base + s * 16);
    }
  };

  f32x4 acc[8][5];
  #pragma unroll
  for (int mi = 0; mi < 8; ++mi)
    #pragma unroll
    for (int ni = 0; ni < 5; ++ni)
      acc[mi][ni] = (f32x4){0.f, 0.f, 0.f, 0.f};

  auto compute = [&](int abufi, int bbufi) {
    const f32x4* Af = (const f32x4*)((char*)lds + abufi * ABYTES);
    const u16*   Bb = (const u16*)((char*)lds + BBASE + bbufi * BBYTES);
    bf16x8 bfr[5];
    #pragma unroll
    for (int ni = 0; ni < 5; ++ni) {
      int n = wvn + ni * 16 + l16;
      int slot = n * 4 + (lhi ^ (n & 3));
      bfr[ni] = *reinterpret_cast<const bf16x8*>(Bb + slot * 8);
    }
    #pragma unroll
    for (int mi = 0; mi < 8; ++mi) {
      int R = wm * 128 + mi * 16 + l16;
      f32x4 a0 = Af[R * 8 + ((2 * lhi)     ^ (R & 7))];
      f32x4 a1 = Af[R * 8 + ((2 * lhi + 1) ^ (R & 7))];
      u32x4 amu = { pk2(a0[0], a0[1]), pk2(a0[2], a0[3]),
                    pk2(a1[0], a1[1]), pk2(a1[2], a1[3]) };
      bf16x8 am = __builtin_bit_cast(bf16x8, amu);
      #pragma unroll
      for (int ni = 0; ni < 5; ++ni)
        acc[mi][ni] = __builtin_amdgcn_mfma_f32_16x16x32_bf16(am, bfr[ni], acc[mi][ni], 0, 0, 0);
    }
  };

  // ---- prologue: A(0), B(0), A(1) issued; keep A(1) in flight ----
  stageA(0, 0);
  stageB(0, 0);
  stageA(1, 1);
  asm volatile("s_waitcnt vmcnt(4)" ::: "memory");   // drain A(0),B(0); keep A(1)
  __builtin_amdgcn_s_barrier();
  __builtin_amdgcn_sched_barrier(0);

  // ---- main loop: 25 uniform steps, counted vmcnt, one barrier/step ----
  for (int t = 0; t < NSTEP; ++t) {
    stageB((t + 1) & 1, t + 1);        // 3 gll (dummy at t=24)
    stageA((t + 2) % 3, t + 2);        // 4 gll (dummy at t>=23)
    __builtin_amdgcn_sched_barrier(0);
    compute(t % 3, t & 1);
    __builtin_amdgcn_sched_barrier(0);
    asm volatile("s_waitcnt vmcnt(4)" ::: "memory");  // drain A(t+1),B(t+1); keep A(t+2)
    __builtin_amdgcn_s_barrier();
    __builtin_amdgcn_sched_barrier(0);
  }
  __syncthreads();    // full drain (incl. dummies) before LDS overlay

  // ---- epilogue: h1 = relu(acc + b1); out = h1 @ w2 + b2, 4 passes of 64 rows ----
  u16* H1  = lds;                  // [64][328] = 41984 B
  u16* W2T = lds + 20992;          // [16][328] = 10496 B (ends 52480 <= 139264)

  for (int i = tid; i < 16 * NP; i += NTHR) {
    int d = i / NP, n = i - (i / NP) * NP;
    float v = (d < DDIM && n < NDIM) ? w2[n * DDIM + d] : 0.f;
    W2T[d * H1STR + n] = f2bf(v);
  }
  float biasv[5];
  #pragma unroll
  for (int ni = 0; ni < 5; ++ni) {
    int col = wvn + ni * 16 + l16;
    biasv[ni] = (col < NDIM) ? b1[col] : 0.f;
  }

  #pragma unroll
  for (int p = 0; p < 4; ++p) {
    if (wm == (p >> 1)) {
      #pragma unroll
      for (int mj = 0; mj < 4; ++mj) {
        int mi = (p & 1) * 4 + mj;
        #pragma unroll
        for (int ni = 0; ni < 5; ++ni) {
          int col = wvn + ni * 16 + l16;
          int rb  = mj * 16 + lhi * 4;
          #pragma unroll
          for (int r = 0; r < 4; ++r) {
            float h = acc[mi][ni][r] + biasv[ni];
            H1[(rb + r) * H1STR + col] = f2bf(fmaxf(h, 0.f));
          }
        }
      }
    }
    __syncthreads();               // H1 (and W2T on p==0) visible
    if (wv < 4) {
      f32x4 a2c = (f32x4){0.f, 0.f, 0.f, 0.f};
      #pragma unroll
      for (int ks = 0; ks < NP / 32; ++ks) {
        bf16x8 a2 = *reinterpret_cast<const bf16x8*>(
            H1 + (wv * 16 + l16) * H1STR + ks * 32 + lhi * 8);
        bf16x8 bw = *reinterpret_cast<const bf16x8*>(
            W2T + l16 * H1STR + ks * 32 + lhi * 8);
        a2c = __builtin_amdgcn_mfma_f32_16x16x32_bf16(a2, bw, a2c, 0, 0, 0);
      }
      if (l16 < DDIM) {
        float bb = b2[l16];
        #pragma unroll
        for (int r = 0; r < 4; ++r) {
          int row = bm + p * 64 + wv * 16 + lhi * 4 + r;
          out[(size_t)row * DDIM + l16] = a2c[r] + bb;
        }
      }
    }
    __syncthreads();               // before next pass overwrites H1
  }
}

extern "C" void kernel_launch(void* const* d_in, const int* in_sizes, int n_in,
                              void* d_out, int out_size, void* d_ws, size_t ws_size,
                              hipStream_t stream) {
  const float* x  = (const float*)d_in[0];
  const float* cw = (const float*)d_in[1];
  const float* w1 = (const float*)d_in[2];
  const float* b1 = (const float*)d_in[3];
  const float* w2 = (const float*)d_in[4];
  const float* b2 = (const float*)d_in[5];
  float* out = (float*)d_out;
  u16* weff = (u16*)d_ws;   // 320*800*2 = 512000 bytes

  hipLaunchKernelGGL(build_weff, dim3((NP * KP + 255) / 256), dim3(256), 0, stream,
                     cw, w1, weff);
  hipLaunchKernelGGL(fused_mlp, dim3(NROW / BM), dim3(NTHR), 0, stream,
                     x, b1, w2, b2, weff, out);
}